// Round 2
// baseline (1116.830 us; speedup 1.0000x reference)
//
#include <hip/hip_runtime.h>

#define N_NODES 100000
#define N_EDGES 1600000
#define N_GRAPHS 512
#define MPAD 100032   // 1563 * 64

typedef unsigned short ushortT;
typedef __attribute__((ext_vector_type(8))) short bf16x8;
typedef __attribute__((ext_vector_type(4))) float f32x4;
typedef __attribute__((ext_vector_type(4))) unsigned int uint4v;

__device__ inline float bf2f(ushortT u) {
    unsigned int x = ((unsigned int)u) << 16;
    return __builtin_bit_cast(float, x);
}
__device__ inline ushortT f2bf(float f) {
    unsigned int x = __builtin_bit_cast(unsigned int, f);
    unsigned int r = (x + 0x7fffu + ((x >> 16) & 1u)) >> 16;
    return (ushortT)r;
}

// ---------------- prep: transpose fp32 weights -> bf16 Wt (fold BN scale), build add vectors ----
__global__ __launch_bounds__(256) void k_prep(
    const float* __restrict__ w11, const float* __restrict__ w12,
    const float* __restrict__ w21, const float* __restrict__ w22,
    const float* __restrict__ w31, const float* __restrict__ w32,
    const float* __restrict__ b11, const float* __restrict__ g1, const float* __restrict__ be1, const float* __restrict__ b12,
    const float* __restrict__ b21, const float* __restrict__ g2, const float* __restrict__ be2, const float* __restrict__ b22,
    const float* __restrict__ b31, const float* __restrict__ g3, const float* __restrict__ be3, const float* __restrict__ b32,
    ushortT* __restrict__ Wt, float* __restrict__ addv)
{
    int bid = blockIdx.x, t = threadIdx.x;
    const float rs = rsqrtf(1.0f + 1e-5f);
    if (bid < 384) {
        int idx = bid * 256 + t;             // 0..98303
        int m = idx >> 14;                   // matrix 0..5
        int r = idx & 16383;
        int k = r & 127;
        int n = r >> 7;
        const float* W = (m == 0) ? w11 : (m == 1) ? w12 : (m == 2) ? w21
                       : (m == 3) ? w22 : (m == 4) ? w31 : w32;
        float v = W[k * 128 + n];
        if ((m & 1) == 0) {                  // a "w1": fold BN scale per out-col n
            const float* gm = (m == 0) ? g1 : (m == 2) ? g2 : g3;
            v *= gm[n] * rs;
        }
        Wt[m * 16384 + n * 128 + k] = f2bf(v);
    } else if (bid == 384) {                 // gemm1 adds: b1*s + beta, matrices 0,2,4
        if (t < 384) {
            int L = t >> 7, n = t & 127;
            const float* bb = (L == 0) ? b11 : (L == 1) ? b21 : b31;
            const float* gm = (L == 0) ? g1 : (L == 1) ? g2 : g3;
            const float* be = (L == 0) ? be1 : (L == 1) ? be2 : be3;
            float s = gm[n] * rs;
            addv[(2 * L) * 128 + n] = bb[n] * s + be[n];
        }
    } else {                                 // gemm2 adds: b2, matrices 1,3,5
        if (t < 384) {
            int L = t >> 7, n = t & 127;
            const float* bb = (L == 0) ? b12 : (L == 1) ? b22 : b32;
            addv[(2 * L + 1) * 128 + n] = bb[n];
        }
    }
}

// ---------------- CSR build ----------------
__global__ __launch_bounds__(256) void k_count(const int* __restrict__ dst, int* __restrict__ deg) {
    int e = blockIdx.x * 256 + threadIdx.x;
    if (e < N_EDGES) atomicAdd(&deg[dst[e]], 1);
}

__global__ __launch_bounds__(1024) void k_scan1(const int* __restrict__ deg, int* __restrict__ tscan,
                                                int* __restrict__ bsum) {
    __shared__ int s[1024];
    int t = threadIdx.x;
    int i = blockIdx.x * 1024 + t;
    int v = (i < N_NODES) ? deg[i] : 0;
    s[t] = v;
    __syncthreads();
    for (int off = 1; off < 1024; off <<= 1) {
        int tmp = (t >= off) ? s[t - off] : 0;
        __syncthreads();
        s[t] += tmp;
        __syncthreads();
    }
    tscan[i] = s[t];
    if (t == 1023) bsum[blockIdx.x] = s[1023];
}

__global__ void k_scan2(const int* __restrict__ bsum, int* __restrict__ boff) {
    if (threadIdx.x == 0 && blockIdx.x == 0) {
        int run = 0;
        for (int b = 0; b < 98; ++b) { boff[b] = run; run += bsum[b]; }
    }
}

__global__ __launch_bounds__(256) void k_scan3(const int* __restrict__ tscan, const int* __restrict__ boff,
                                               int* __restrict__ indptr) {
    int i = blockIdx.x * 256 + threadIdx.x;
    if (i > N_NODES) return;
    indptr[i] = (i == 0) ? 0 : tscan[i - 1] + boff[(i - 1) >> 10];
}

__global__ __launch_bounds__(256) void k_fill(const int* __restrict__ src, const int* __restrict__ dst,
                                              const int* __restrict__ indptr, int* __restrict__ cur,
                                              int* __restrict__ col) {
    int e = blockIdx.x * 256 + threadIdx.x;
    if (e < N_EDGES) {
        int d = dst[e];
        int pos = indptr[d] + atomicAdd(&cur[d], 1);
        col[pos] = src[e];
    }
}

// ------- aggregation (fp32 input): T[i] = bf16(x[i] + sum_{j in CSR(i)} x[col[j]]) -------
__global__ __launch_bounds__(256) void k_agg_f32(const float* __restrict__ X, const int* __restrict__ indptr,
                                                 const int* __restrict__ col, ushortT* __restrict__ T) {
    int gid = blockIdx.x * 4 + (threadIdx.x >> 6);
    int lane = threadIdx.x & 63;
    if (gid >= MPAD) return;
    if (gid >= N_NODES) {                    // zero padding rows (MFMA A-operand hygiene)
        *(unsigned int*)&T[(size_t)gid * 128 + lane * 2] = 0u;
        return;
    }
    int lo = indptr[gid], hi = indptr[gid + 1];
    float2 v = *(const float2*)&X[(size_t)gid * 128 + lane * 2];
    float ax = v.x, ay = v.y;
    for (int j = lo; j < hi; ++j) {
        int c = col[j];
        float2 u = *(const float2*)&X[(size_t)c * 128 + lane * 2];
        ax += u.x;
        ay += u.y;
    }
    unsigned int o = ((unsigned int)f2bf(ay) << 16) | (unsigned int)f2bf(ax);
    *(unsigned int*)&T[(size_t)gid * 128 + lane * 2] = o;
}

// ------- aggregation (bf16 input) -------
__global__ __launch_bounds__(256) void k_agg_bf(const ushortT* __restrict__ X, const int* __restrict__ indptr,
                                                const int* __restrict__ col, ushortT* __restrict__ T) {
    int gid = blockIdx.x * 4 + (threadIdx.x >> 6);
    int lane = threadIdx.x & 63;
    if (gid >= MPAD) return;
    if (gid >= N_NODES) {
        *(unsigned int*)&T[(size_t)gid * 128 + lane * 2] = 0u;
        return;
    }
    int lo = indptr[gid], hi = indptr[gid + 1];
    unsigned int v = *(const unsigned int*)&X[(size_t)gid * 128 + lane * 2];
    float ax = bf2f((ushortT)(v & 0xffff));
    float ay = bf2f((ushortT)(v >> 16));
    for (int j = lo; j < hi; ++j) {
        int c = col[j];
        unsigned int u = *(const unsigned int*)&X[(size_t)c * 128 + lane * 2];
        ax += bf2f((ushortT)(u & 0xffff));
        ay += bf2f((ushortT)(u >> 16));
    }
    unsigned int o = ((unsigned int)f2bf(ay) << 16) | (unsigned int)f2bf(ax);
    *(unsigned int*)&T[(size_t)gid * 128 + lane * 2] = o;
}

// ---------------- GEMM: C = bf16(relu(A @ W + add)),  A:[MPAD][128] bf16, Wt:[128(n)][128(k)] ----
__global__ __launch_bounds__(256) void k_gemm(const ushortT* __restrict__ A, const ushortT* __restrict__ Wt,
                                              const float* __restrict__ addv, ushortT* __restrict__ C) {
    __shared__ ushortT w[128 * 136];         // Wt staged, row stride 136 (2-way bank alias only)
    int tid = threadIdx.x;
    for (int it = 0; it < 8; ++it) {
        int idx = (it * 256 + tid) * 8;      // element index, 16B per thread
        int n = idx >> 7, k = idx & 127;
        *(uint4v*)&w[n * 136 + k] = *(const uint4v*)&Wt[idx];
    }
    __syncthreads();
    int wave = tid >> 6, lane = tid & 63;
    int quad = lane >> 4, l16 = lane & 15;
    int row0 = blockIdx.x * 64 + wave * 16;
    f32x4 acc[8];
#pragma unroll
    for (int c = 0; c < 8; ++c) acc[c] = (f32x4){0.f, 0.f, 0.f, 0.f};
    const ushortT* arow = A + (size_t)(row0 + l16) * 128;
#pragma unroll
    for (int kc = 0; kc < 4; ++kc) {
        bf16x8 af = *(const bf16x8*)&arow[kc * 32 + quad * 8];
#pragma unroll
        for (int c = 0; c < 8; ++c) {
            bf16x8 bf = *(const bf16x8*)&w[(c * 16 + l16) * 136 + kc * 32 + quad * 8];
            acc[c] = __builtin_amdgcn_mfma_f32_16x16x32_bf16(af, bf, acc[c], 0, 0, 0);
        }
    }
#pragma unroll
    for (int c = 0; c < 8; ++c) {
        int n = c * 16 + l16;
        float ad = addv[n];
#pragma unroll
        for (int r = 0; r < 4; ++r) {
            int row = row0 + quad * 4 + r;
            if (row < N_NODES) {
                float y = acc[c][r] + ad;
                y = y > 0.f ? y : 0.f;
                C[(size_t)row * 128 + n] = f2bf(y);
            }
        }
    }
}

// ---------------- pooling: P[g][off+t] = sum over batch==g of H[i][t] ----------
__device__ inline int lbound(const int* b, int n, int v) {
    int lo = 0, hi = n;
    while (lo < hi) { int m = (lo + hi) >> 1; if (b[m] < v) lo = m + 1; else hi = m; }
    return lo;
}

__global__ __launch_bounds__(128) void k_pool(const ushortT* __restrict__ H, const int* __restrict__ batch,
                                              float* __restrict__ P, int off) {
    int g = blockIdx.x, t = threadIdx.x;
    int lo = lbound(batch, N_NODES, g);
    int hi = lbound(batch, N_NODES, g + 1);
    float a = 0.f;
    for (int i = lo; i < hi; ++i) a += bf2f(H[(size_t)i * 128 + t]);
    P[g * 384 + off + t] = a;
}

// ---------------- head: out = relu(P @ W1 + b1) @ W2 + b2  (all fp32) ------------
__global__ __launch_bounds__(384) void k_head(const float* __restrict__ P, const float* __restrict__ W1,
                                              const float* __restrict__ B1, const float* __restrict__ W2,
                                              const float* __restrict__ B2, float* __restrict__ out) {
    __shared__ float pr[384];
    __shared__ float qr[384];
    int g = blockIdx.x, t = threadIdx.x;
    pr[t] = P[g * 384 + t];
    __syncthreads();
    float a = 0.f;
    for (int k = 0; k < 384; ++k) a += pr[k] * W1[k * 384 + t];
    a += B1[t];
    qr[t] = a > 0.f ? a : 0.f;
    __syncthreads();
    if (t < 10) {
        float o = 0.f;
        for (int k = 0; k < 384; ++k) o += qr[k] * W2[k * 10 + t];
        o += B2[t];
        out[g * 10 + t] = o;
    }
}

extern "C" void kernel_launch(void* const* d_in, const int* in_sizes, int n_in,
                              void* d_out, int out_size, void* d_ws, size_t ws_size,
                              hipStream_t stream) {
    const float* x     = (const float*)d_in[0];
    const int*   ei    = (const int*)d_in[1];
    const int*   srcA  = ei;
    const int*   dstA  = ei + N_EDGES;
    const int*   batch = (const int*)d_in[2];
    const float* c1_w1 = (const float*)d_in[3];
    const float* c1_b1 = (const float*)d_in[4];
    const float* c1_g  = (const float*)d_in[5];
    const float* c1_be = (const float*)d_in[6];
    const float* c1_w2 = (const float*)d_in[7];
    const float* c1_b2 = (const float*)d_in[8];
    const float* c2_w1 = (const float*)d_in[9];
    const float* c2_b1 = (const float*)d_in[10];
    const float* c2_g  = (const float*)d_in[11];
    const float* c2_be = (const float*)d_in[12];
    const float* c2_w2 = (const float*)d_in[13];
    const float* c2_b2 = (const float*)d_in[14];
    const float* c3_w1 = (const float*)d_in[15];
    const float* c3_b1 = (const float*)d_in[16];
    const float* c3_g  = (const float*)d_in[17];
    const float* c3_be = (const float*)d_in[18];
    const float* c3_w2 = (const float*)d_in[19];
    const float* c3_b2 = (const float*)d_in[20];
    const float* l1w   = (const float*)d_in[21];
    const float* l1b   = (const float*)d_in[22];
    const float* l2w   = (const float*)d_in[23];
    const float* l2b   = (const float*)d_in[24];
    float* out = (float*)d_out;

    size_t o = 0;
    char* base = (char*)d_ws;
    auto alloc = [&](size_t n) -> char* {
        char* p = base + o;
        o += (n + 255) & ~(size_t)255;
        return p;
    };
    ushortT* Wt    = (ushortT*)alloc(6 * 16384 * 2);
    float*   addv  = (float*)alloc(6 * 128 * 4);
    int*     deg   = (int*)alloc((size_t)N_NODES * 4);
    int*     cur   = (int*)alloc((size_t)N_NODES * 4);
    int*     tscan = (int*)alloc((size_t)100352 * 4);
    int*     bsum  = (int*)alloc(98 * 4);
    int*     boff  = (int*)alloc(98 * 4);
    int*     iptr  = (int*)alloc((size_t)(N_NODES + 1) * 4);
    int*     colA  = (int*)alloc((size_t)N_EDGES * 4);
    ushortT* bufA  = (ushortT*)alloc((size_t)MPAD * 128 * 2);   // agg output
    ushortT* bufB  = (ushortT*)alloc((size_t)MPAD * 128 * 2);   // gemm1 output
    ushortT* bufC  = (ushortT*)alloc((size_t)MPAD * 128 * 2);   // gemm2 output / next input
    float*   pbuf  = (float*)alloc((size_t)N_GRAPHS * 384 * 4);

    hipMemsetAsync(deg, 0, (size_t)N_NODES * 4, stream);
    hipMemsetAsync(cur, 0, (size_t)N_NODES * 4, stream);

    k_prep<<<386, 256, 0, stream>>>(c1_w1, c1_w2, c2_w1, c2_w2, c3_w1, c3_w2,
                                    c1_b1, c1_g, c1_be, c1_b2,
                                    c2_b1, c2_g, c2_be, c2_b2,
                                    c3_b1, c3_g, c3_be, c3_b2,
                                    Wt, addv);
    k_count<<<N_EDGES / 256, 256, 0, stream>>>(dstA, deg);
    k_scan1<<<98, 1024, 0, stream>>>(deg, tscan, bsum);
    k_scan2<<<1, 64, 0, stream>>>(bsum, boff);
    k_scan3<<<391, 256, 0, stream>>>(tscan, boff, iptr);
    k_fill<<<N_EDGES / 256, 256, 0, stream>>>(srcA, dstA, iptr, cur, colA);

    for (int L = 0; L < 3; ++L) {
        if (L == 0)
            k_agg_f32<<<MPAD / 4, 256, 0, stream>>>(x, iptr, colA, bufA);
        else
            k_agg_bf<<<MPAD / 4, 256, 0, stream>>>(bufC, iptr, colA, bufA);
        k_gemm<<<MPAD / 64, 256, 0, stream>>>(bufA, Wt + (2 * L) * 16384, addv + (2 * L) * 128, bufB);
        k_gemm<<<MPAD / 64, 256, 0, stream>>>(bufB, Wt + (2 * L + 1) * 16384, addv + (2 * L + 1) * 128, bufC);
        k_pool<<<N_GRAPHS, 128, 0, stream>>>(bufC, batch, pbuf, L * 128);
    }
    k_head<<<N_GRAPHS, 384, 0, stream>>>(pbuf, l1w, l1b, l2w, l2b, out);
}

// Round 3
// 1101.891 us; speedup vs baseline: 1.0136x; 1.0136x over previous
//
#include <hip/hip_runtime.h>

#define N_NODES 100000
#define N_EDGES 1600000
#define N_GRAPHS 512
#define MPAD 100096   // 782 * 128

typedef unsigned short ushortT;
typedef __attribute__((ext_vector_type(8))) short bf16x8;
typedef __attribute__((ext_vector_type(4))) float f32x4;
typedef __attribute__((ext_vector_type(4))) unsigned int uint4v;

__device__ inline float bf2f(ushortT u) {
    unsigned int x = ((unsigned int)u) << 16;
    return __builtin_bit_cast(float, x);
}
__device__ inline ushortT f2bf(float f) {
    unsigned int x = __builtin_bit_cast(unsigned int, f);
    unsigned int r = (x + 0x7fffu + ((x >> 16) & 1u)) >> 16;
    return (ushortT)r;
}

// ---------------- prep: transpose fp32 weights -> bf16 Wt (fold BN scale), build add vectors ----
__global__ __launch_bounds__(256) void k_prep(
    const float* __restrict__ w11, const float* __restrict__ w12,
    const float* __restrict__ w21, const float* __restrict__ w22,
    const float* __restrict__ w31, const float* __restrict__ w32,
    const float* __restrict__ b11, const float* __restrict__ g1, const float* __restrict__ be1, const float* __restrict__ b12,
    const float* __restrict__ b21, const float* __restrict__ g2, const float* __restrict__ be2, const float* __restrict__ b22,
    const float* __restrict__ b31, const float* __restrict__ g3, const float* __restrict__ be3, const float* __restrict__ b32,
    ushortT* __restrict__ Wt, float* __restrict__ addv)
{
    int bid = blockIdx.x, t = threadIdx.x;
    const float rs = rsqrtf(1.0f + 1e-5f);
    if (bid < 384) {
        int idx = bid * 256 + t;             // 0..98303
        int m = idx >> 14;                   // matrix 0..5
        int r = idx & 16383;
        int k = r & 127;
        int n = r >> 7;
        const float* W = (m == 0) ? w11 : (m == 1) ? w12 : (m == 2) ? w21
                       : (m == 3) ? w22 : (m == 4) ? w31 : w32;
        float v = W[k * 128 + n];
        if ((m & 1) == 0) {                  // a "w1": fold BN scale per out-col n
            const float* gm = (m == 0) ? g1 : (m == 2) ? g2 : g3;
            v *= gm[n] * rs;
        }
        Wt[m * 16384 + n * 128 + k] = f2bf(v);
    } else if (bid == 384) {                 // gemm1 adds: b1*s + beta
        if (t < 384) {
            int L = t >> 7, n = t & 127;
            const float* bb = (L == 0) ? b11 : (L == 1) ? b21 : b31;
            const float* gm = (L == 0) ? g1 : (L == 1) ? g2 : g3;
            const float* be = (L == 0) ? be1 : (L == 1) ? be2 : be3;
            float s = gm[n] * rs;
            addv[(2 * L) * 128 + n] = bb[n] * s + be[n];
        }
    } else {                                 // gemm2 adds: b2
        if (t < 384) {
            int L = t >> 7, n = t & 127;
            const float* bb = (L == 0) ? b12 : (L == 1) ? b22 : b32;
            addv[(2 * L + 1) * 128 + n] = bb[n];
        }
    }
}

// ---------------- x (fp32) -> bf16, plus zeroed padding rows ----------------
__global__ __launch_bounds__(256) void k_cvt(const float* __restrict__ X, ushortT* __restrict__ Y) {
    size_t i = ((size_t)blockIdx.x * 256 + threadIdx.x) * 4;
    if (i >= (size_t)MPAD * 128) return;
    unsigned long long o = 0ull;
    if (i < (size_t)N_NODES * 128) {
        float4 v = *(const float4*)&X[i];
        o = (unsigned long long)f2bf(v.x)
          | ((unsigned long long)f2bf(v.y) << 16)
          | ((unsigned long long)f2bf(v.z) << 32)
          | ((unsigned long long)f2bf(v.w) << 48);
    }
    *(unsigned long long*)&Y[i] = o;
}

// ---------------- CSR build ----------------
__global__ __launch_bounds__(256) void k_count(const int* __restrict__ dst, int* __restrict__ deg) {
    int e = blockIdx.x * 256 + threadIdx.x;
    if (e < N_EDGES) atomicAdd(&deg[dst[e]], 1);
}

__global__ __launch_bounds__(1024) void k_scan1(const int* __restrict__ deg, int* __restrict__ tscan,
                                                int* __restrict__ bsum) {
    __shared__ int s[1024];
    int t = threadIdx.x;
    int i = blockIdx.x * 1024 + t;
    int v = (i < N_NODES) ? deg[i] : 0;
    s[t] = v;
    __syncthreads();
    for (int off = 1; off < 1024; off <<= 1) {
        int tmp = (t >= off) ? s[t - off] : 0;
        __syncthreads();
        s[t] += tmp;
        __syncthreads();
    }
    tscan[i] = s[t];
    if (t == 1023) bsum[blockIdx.x] = s[1023];
}

__global__ void k_scan2(const int* __restrict__ bsum, int* __restrict__ boff) {
    if (threadIdx.x == 0 && blockIdx.x == 0) {
        int run = 0;
        for (int b = 0; b < 98; ++b) { boff[b] = run; run += bsum[b]; }
    }
}

__global__ __launch_bounds__(256) void k_scan3(const int* __restrict__ tscan, const int* __restrict__ boff,
                                               int* __restrict__ indptr) {
    int i = blockIdx.x * 256 + threadIdx.x;
    if (i > N_NODES) return;
    indptr[i] = (i == 0) ? 0 : tscan[i - 1] + boff[(i - 1) >> 10];
}

__global__ __launch_bounds__(256) void k_fill(const int* __restrict__ src, const int* __restrict__ dst,
                                              const int* __restrict__ indptr, int* __restrict__ cur,
                                              int* __restrict__ col) {
    int e = blockIdx.x * 256 + threadIdx.x;
    if (e < N_EDGES) {
        int d = dst[e];
        int pos = indptr[d] + atomicAdd(&cur[d], 1);
        col[pos] = src[e];
    }
}

// ------- aggregation (bf16): T[i] = bf16(X[i] + sum_{j in CSR(i)} X[col[j]]) -------
__global__ __launch_bounds__(256) void k_agg(const ushortT* __restrict__ X, const int* __restrict__ indptr,
                                             const int* __restrict__ col, ushortT* __restrict__ T) {
    int gid = blockIdx.x * 4 + (threadIdx.x >> 6);
    int lane = threadIdx.x & 63;
    if (gid >= MPAD) return;
    if (gid >= N_NODES) {                    // zero padding rows (MFMA A-operand hygiene)
        *(unsigned int*)&T[(size_t)gid * 128 + lane * 2] = 0u;
        return;
    }
    int lo = indptr[gid], hi = indptr[gid + 1];
    unsigned int v = *(const unsigned int*)&X[(size_t)gid * 128 + lane * 2];
    float ax = bf2f((ushortT)(v & 0xffff));
    float ay = bf2f((ushortT)(v >> 16));
    for (int j = lo; j < hi; ++j) {
        int c = col[j];
        unsigned int u = *(const unsigned int*)&X[(size_t)c * 128 + lane * 2];
        ax += bf2f((ushortT)(u & 0xffff));
        ay += bf2f((ushortT)(u >> 16));
    }
    unsigned int o = ((unsigned int)f2bf(ay) << 16) | (unsigned int)f2bf(ax);
    *(unsigned int*)&T[(size_t)gid * 128 + lane * 2] = o;
}

// ---------------- GEMM: C = bf16(relu(A @ W + add)), 128 rows/block ----------------
__global__ __launch_bounds__(256) void k_gemm(const ushortT* __restrict__ A, const ushortT* __restrict__ Wt,
                                              const float* __restrict__ addv, ushortT* __restrict__ C) {
    __shared__ ushortT w[128 * 136];         // Wt staged, row stride 136 (2-way bank alias only)
    int tid = threadIdx.x;
#pragma unroll
    for (int it = 0; it < 8; ++it) {
        int idx = (it * 256 + tid) * 8;      // element index, 16B per thread
        int n = idx >> 7, k = idx & 127;
        *(uint4v*)&w[n * 136 + k] = *(const uint4v*)&Wt[idx];
    }
    __syncthreads();
    int wave = tid >> 6, lane = tid & 63;
    int quad = lane >> 4, l16 = lane & 15;
    int row0 = blockIdx.x * 128 + wave * 32;
    f32x4 acc[2][8];
#pragma unroll
    for (int t2 = 0; t2 < 2; ++t2)
#pragma unroll
        for (int c = 0; c < 8; ++c) acc[t2][c] = (f32x4){0.f, 0.f, 0.f, 0.f};
    const ushortT* ar0 = A + (size_t)(row0 + l16) * 128;
    const ushortT* ar1 = A + (size_t)(row0 + 16 + l16) * 128;
#pragma unroll
    for (int kc = 0; kc < 4; ++kc) {
        bf16x8 a0 = *(const bf16x8*)&ar0[kc * 32 + quad * 8];
        bf16x8 a1 = *(const bf16x8*)&ar1[kc * 32 + quad * 8];
#pragma unroll
        for (int c = 0; c < 8; ++c) {
            bf16x8 bf = *(const bf16x8*)&w[(c * 16 + l16) * 136 + kc * 32 + quad * 8];
            acc[0][c] = __builtin_amdgcn_mfma_f32_16x16x32_bf16(a0, bf, acc[0][c], 0, 0, 0);
            acc[1][c] = __builtin_amdgcn_mfma_f32_16x16x32_bf16(a1, bf, acc[1][c], 0, 0, 0);
        }
    }
#pragma unroll
    for (int t2 = 0; t2 < 2; ++t2) {
#pragma unroll
        for (int c = 0; c < 8; ++c) {
            int n = c * 16 + l16;
            float ad = addv[n];
#pragma unroll
            for (int r = 0; r < 4; ++r) {
                int row = row0 + t2 * 16 + quad * 4 + r;
                if (row < N_NODES) {
                    float y = acc[t2][c][r] + ad;
                    y = y > 0.f ? y : 0.f;
                    C[(size_t)row * 128 + n] = f2bf(y);
                }
            }
        }
    }
}

// ------- pooling: chunk-parallel run-length accumulation (batch is sorted) -------
#define POOL_CHUNK 512
__global__ __launch_bounds__(256) void k_pool(const ushortT* __restrict__ H, const int* __restrict__ batch,
                                              float* __restrict__ P, int off) {
    int n0 = blockIdx.x * POOL_CHUNK;
    int d = threadIdx.x & 127;
    int s = threadIdx.x >> 7;                // 2 interleaved node streams
    int end = n0 + POOL_CHUNK;
    if (end > N_NODES) end = N_NODES;
    float acc = 0.f;
    int cur = -1;
    for (int i = n0 + s; i < end; i += 2) {
        int gi = batch[i];
        float v = bf2f(H[(size_t)i * 128 + d]);
        if (gi != cur) {
            if (cur >= 0) atomicAdd(&P[cur * 384 + off + d], acc);
            cur = gi;
            acc = 0.f;
        }
        acc += v;
    }
    if (cur >= 0) atomicAdd(&P[cur * 384 + off + d], acc);
}

// ---------------- head: out = relu(P @ W1 + b1) @ W2 + b2  (all fp32) ------------
__global__ __launch_bounds__(384) void k_head(const float* __restrict__ P, const float* __restrict__ W1,
                                              const float* __restrict__ B1, const float* __restrict__ W2,
                                              const float* __restrict__ B2, float* __restrict__ out) {
    __shared__ float pr[384];
    __shared__ float qr[384];
    int g = blockIdx.x, t = threadIdx.x;
    pr[t] = P[g * 384 + t];
    __syncthreads();
    float a = 0.f;
    for (int k = 0; k < 384; ++k) a += pr[k] * W1[k * 384 + t];
    a += B1[t];
    qr[t] = a > 0.f ? a : 0.f;
    __syncthreads();
    if (t < 10) {
        float o = 0.f;
        for (int k = 0; k < 384; ++k) o += qr[k] * W2[k * 10 + t];
        o += B2[t];
        out[g * 10 + t] = o;
    }
}

extern "C" void kernel_launch(void* const* d_in, const int* in_sizes, int n_in,
                              void* d_out, int out_size, void* d_ws, size_t ws_size,
                              hipStream_t stream) {
    const float* x     = (const float*)d_in[0];
    const int*   ei    = (const int*)d_in[1];
    const int*   srcA  = ei;
    const int*   dstA  = ei + N_EDGES;
    const int*   batch = (const int*)d_in[2];
    const float* c1_w1 = (const float*)d_in[3];
    const float* c1_b1 = (const float*)d_in[4];
    const float* c1_g  = (const float*)d_in[5];
    const float* c1_be = (const float*)d_in[6];
    const float* c1_w2 = (const float*)d_in[7];
    const float* c1_b2 = (const float*)d_in[8];
    const float* c2_w1 = (const float*)d_in[9];
    const float* c2_b1 = (const float*)d_in[10];
    const float* c2_g  = (const float*)d_in[11];
    const float* c2_be = (const float*)d_in[12];
    const float* c2_w2 = (const float*)d_in[13];
    const float* c2_b2 = (const float*)d_in[14];
    const float* c3_w1 = (const float*)d_in[15];
    const float* c3_b1 = (const float*)d_in[16];
    const float* c3_g  = (const float*)d_in[17];
    const float* c3_be = (const float*)d_in[18];
    const float* c3_w2 = (const float*)d_in[19];
    const float* c3_b2 = (const float*)d_in[20];
    const float* l1w   = (const float*)d_in[21];
    const float* l1b   = (const float*)d_in[22];
    const float* l2w   = (const float*)d_in[23];
    const float* l2b   = (const float*)d_in[24];
    float* out = (float*)d_out;

    size_t o = 0;
    char* base = (char*)d_ws;
    auto alloc = [&](size_t n) -> char* {
        char* p = base + o;
        o += (n + 255) & ~(size_t)255;
        return p;
    };
    ushortT* Wt    = (ushortT*)alloc(6 * 16384 * 2);
    float*   addv  = (float*)alloc(6 * 128 * 4);
    int*     deg   = (int*)alloc((size_t)N_NODES * 4);
    int*     cur   = (int*)alloc((size_t)N_NODES * 4);
    int*     tscan = (int*)alloc((size_t)100352 * 4);
    int*     bsum  = (int*)alloc(98 * 4);
    int*     boff  = (int*)alloc(98 * 4);
    int*     iptr  = (int*)alloc((size_t)(N_NODES + 1) * 4);
    int*     colA  = (int*)alloc((size_t)N_EDGES * 4);
    ushortT* bufA  = (ushortT*)alloc((size_t)MPAD * 128 * 2);   // agg output
    ushortT* bufB  = (ushortT*)alloc((size_t)MPAD * 128 * 2);   // gemm1 output
    ushortT* bufC  = (ushortT*)alloc((size_t)MPAD * 128 * 2);   // x(bf16) / gemm2 output
    float*   pbuf  = (float*)alloc((size_t)N_GRAPHS * 384 * 4);

    hipMemsetAsync(deg, 0, (size_t)N_NODES * 4, stream);
    hipMemsetAsync(cur, 0, (size_t)N_NODES * 4, stream);
    hipMemsetAsync(pbuf, 0, (size_t)N_GRAPHS * 384 * 4, stream);

    k_prep<<<386, 256, 0, stream>>>(c1_w1, c1_w2, c2_w1, c2_w2, c3_w1, c3_w2,
                                    c1_b1, c1_g, c1_be, c1_b2,
                                    c2_b1, c2_g, c2_be, c2_b2,
                                    c3_b1, c3_g, c3_be, c3_b2,
                                    Wt, addv);
    k_cvt<<<(MPAD * 128 / 4 + 255) / 256, 256, 0, stream>>>(x, bufC);
    k_count<<<N_EDGES / 256, 256, 0, stream>>>(dstA, deg);
    k_scan1<<<98, 1024, 0, stream>>>(deg, tscan, bsum);
    k_scan2<<<1, 64, 0, stream>>>(bsum, boff);
    k_scan3<<<391, 256, 0, stream>>>(tscan, boff, iptr);
    k_fill<<<N_EDGES / 256, 256, 0, stream>>>(srcA, dstA, iptr, cur, colA);

    for (int L = 0; L < 3; ++L) {
        k_agg<<<MPAD / 4, 256, 0, stream>>>(bufC, iptr, colA, bufA);
        k_gemm<<<MPAD / 128, 256, 0, stream>>>(bufA, Wt + (2 * L) * 16384, addv + (2 * L) * 128, bufB);
        k_gemm<<<MPAD / 128, 256, 0, stream>>>(bufB, Wt + (2 * L + 1) * 16384, addv + (2 * L + 1) * 128, bufC);
        k_pool<<<(N_NODES + POOL_CHUNK - 1) / POOL_CHUNK, 256, 0, stream>>>(bufC, batch, pbuf, L * 128);
    }
    k_head<<<N_GRAPHS, 384, 0, stream>>>(pbuf, l1w, l1b, l2w, l2b, out);
}

// Round 4
// 676.217 us; speedup vs baseline: 1.6516x; 1.6295x over previous
//
#include <hip/hip_runtime.h>

#define N_NODES 100000
#define N_EDGES 1600000
#define N_GRAPHS 512
#define MPAD 100096   // 782 * 128
#define COL_CAP 2400000  // N_EDGES + 8*N_NODES worst case

typedef unsigned short ushortT;
typedef __attribute__((ext_vector_type(8))) short bf16x8;
typedef __attribute__((ext_vector_type(4))) float f32x4;
typedef __attribute__((ext_vector_type(4))) unsigned int uint4v;

__device__ inline float bf2f(ushortT u) {
    unsigned int x = ((unsigned int)u) << 16;
    return __builtin_bit_cast(float, x);
}
__device__ inline ushortT f2bf(float f) {
    unsigned int x = __builtin_bit_cast(unsigned int, f);
    unsigned int r = (x + 0x7fffu + ((x >> 16) & 1u)) >> 16;
    return (ushortT)r;
}

// ---------------- prep: transpose fp32 weights -> bf16 Wt (fold BN scale), build add vectors ----
__global__ __launch_bounds__(256) void k_prep(
    const float* __restrict__ w11, const float* __restrict__ w12,
    const float* __restrict__ w21, const float* __restrict__ w22,
    const float* __restrict__ w31, const float* __restrict__ w32,
    const float* __restrict__ b11, const float* __restrict__ g1, const float* __restrict__ be1, const float* __restrict__ b12,
    const float* __restrict__ b21, const float* __restrict__ g2, const float* __restrict__ be2, const float* __restrict__ b22,
    const float* __restrict__ b31, const float* __restrict__ g3, const float* __restrict__ be3, const float* __restrict__ b32,
    ushortT* __restrict__ Wt, float* __restrict__ addv)
{
    int bid = blockIdx.x, t = threadIdx.x;
    const float rs = rsqrtf(1.0f + 1e-5f);
    if (bid < 384) {
        int idx = bid * 256 + t;             // 0..98303
        int m = idx >> 14;                   // matrix 0..5
        int r = idx & 16383;
        int k = r & 127;
        int n = r >> 7;
        const float* W = (m == 0) ? w11 : (m == 1) ? w12 : (m == 2) ? w21
                       : (m == 3) ? w22 : (m == 4) ? w31 : w32;
        float v = W[k * 128 + n];
        if ((m & 1) == 0) {                  // a "w1": fold BN scale per out-col n
            const float* gm = (m == 0) ? g1 : (m == 2) ? g2 : g3;
            v *= gm[n] * rs;
        }
        Wt[m * 16384 + n * 128 + k] = f2bf(v);
    } else if (bid == 384) {                 // gemm1 adds: b1*s + beta
        if (t < 384) {
            int L = t >> 7, n = t & 127;
            const float* bb = (L == 0) ? b11 : (L == 1) ? b21 : b31;
            const float* gm = (L == 0) ? g1 : (L == 1) ? g2 : g3;
            const float* be = (L == 0) ? be1 : (L == 1) ? be2 : be3;
            float s = gm[n] * rs;
            addv[(2 * L) * 128 + n] = bb[n] * s + be[n];
        }
    } else {                                 // gemm2 adds: b2
        if (t < 384) {
            int L = t >> 7, n = t & 127;
            const float* bb = (L == 0) ? b12 : (L == 1) ? b22 : b32;
            addv[(2 * L + 1) * 128 + n] = bb[n];
        }
    }
}

// ---------------- x (fp32) -> bf16, plus zeroed padding rows ----------------
__global__ __launch_bounds__(256) void k_cvt(const float* __restrict__ X, ushortT* __restrict__ Y) {
    size_t i = ((size_t)blockIdx.x * 256 + threadIdx.x) * 4;
    if (i >= (size_t)MPAD * 128) return;
    unsigned long long o = 0ull;
    if (i < (size_t)N_NODES * 128) {
        float4 v = *(const float4*)&X[i];
        o = (unsigned long long)f2bf(v.x)
          | ((unsigned long long)f2bf(v.y) << 16)
          | ((unsigned long long)f2bf(v.z) << 32)
          | ((unsigned long long)f2bf(v.w) << 48);
    }
    *(unsigned long long*)&Y[i] = o;
}

// ---------------- CSR build (padded to multiple-of-8 per node) ----------------
__global__ __launch_bounds__(256) void k_count(const int* __restrict__ dst, int* __restrict__ deg) {
    int e = blockIdx.x * 256 + threadIdx.x;
    if (e < N_EDGES) atomicAdd(&deg[dst[e]], 1);
}

__global__ __launch_bounds__(1024) void k_scan1(const int* __restrict__ deg, int* __restrict__ tscan,
                                                int* __restrict__ bsum) {
    __shared__ int s[1024];
    int t = threadIdx.x;
    int i = blockIdx.x * 1024 + t;
    int v = (i < N_NODES) ? ((deg[i] + 7) & ~7) : 0;   // padded degree
    s[t] = v;
    __syncthreads();
    for (int off = 1; off < 1024; off <<= 1) {
        int tmp = (t >= off) ? s[t - off] : 0;
        __syncthreads();
        s[t] += tmp;
        __syncthreads();
    }
    tscan[i] = s[t];
    if (t == 1023) bsum[blockIdx.x] = s[1023];
}

__global__ void k_scan2(const int* __restrict__ bsum, int* __restrict__ boff) {
    if (threadIdx.x == 0 && blockIdx.x == 0) {
        int run = 0;
        for (int b = 0; b < 98; ++b) { boff[b] = run; run += bsum[b]; }
    }
}

__global__ __launch_bounds__(256) void k_scan3(const int* __restrict__ tscan, const int* __restrict__ boff,
                                               int* __restrict__ pstart) {
    int i = blockIdx.x * 256 + threadIdx.x;
    if (i > N_NODES) return;
    pstart[i] = (i == 0) ? 0 : tscan[i - 1] + boff[(i - 1) >> 10];
}

__global__ __launch_bounds__(256) void k_fill(const int* __restrict__ src, const int* __restrict__ dst,
                                              const int* __restrict__ pstart, int* __restrict__ cur,
                                              int* __restrict__ col) {
    int e = blockIdx.x * 256 + threadIdx.x;
    if (e < N_EDGES) {
        int d = dst[e];
        int pos = pstart[d] + atomicAdd(&cur[d], 1);
        col[pos] = src[e];
    }
}

// pad each node's list up to multiple of 8 with index N_NODES (a guaranteed-zero row)
__global__ __launch_bounds__(256) void k_padfill(const int* __restrict__ deg, const int* __restrict__ pstart,
                                                 int* __restrict__ col) {
    int i = blockIdx.x * 256 + threadIdx.x;
    if (i >= N_NODES) return;
    int s = pstart[i] + deg[i];
    int e = pstart[i + 1];
    for (int j = s; j < e; ++j) col[j] = N_NODES;
}

// ------- aggregation (bf16): T[i] = bf16(X[i] + sum_j X[col[j]]), unroll-8 branch-free -------
__global__ __launch_bounds__(256) void k_agg(const ushortT* __restrict__ X, const int* __restrict__ pstart,
                                             const int* __restrict__ col, ushortT* __restrict__ T) {
    int gid = blockIdx.x * 4 + (threadIdx.x >> 6);
    int lane = threadIdx.x & 63;
    if (gid >= MPAD) return;
    if (gid >= N_NODES) {                    // zero padding rows (MFMA A-operand hygiene)
        *(unsigned int*)&T[(size_t)gid * 128 + lane * 2] = 0u;
        return;
    }
    int lo = pstart[gid], hi = pstart[gid + 1];
    unsigned int v = *(const unsigned int*)&X[(size_t)gid * 128 + lane * 2];
    float ax = bf2f((ushortT)(v & 0xffff));
    float ay = bf2f((ushortT)(v >> 16));
    for (int j = lo; j < hi; j += 8) {       // (hi-lo) % 8 == 0 by construction
        int4 c0 = *(const int4*)&col[j];     // 32B-aligned: pstart values are multiples of 8
        int4 c1 = *(const int4*)&col[j + 4];
        unsigned int u0 = *(const unsigned int*)&X[(size_t)c0.x * 128 + lane * 2];
        unsigned int u1 = *(const unsigned int*)&X[(size_t)c0.y * 128 + lane * 2];
        unsigned int u2 = *(const unsigned int*)&X[(size_t)c0.z * 128 + lane * 2];
        unsigned int u3 = *(const unsigned int*)&X[(size_t)c0.w * 128 + lane * 2];
        unsigned int u4 = *(const unsigned int*)&X[(size_t)c1.x * 128 + lane * 2];
        unsigned int u5 = *(const unsigned int*)&X[(size_t)c1.y * 128 + lane * 2];
        unsigned int u6 = *(const unsigned int*)&X[(size_t)c1.z * 128 + lane * 2];
        unsigned int u7 = *(const unsigned int*)&X[(size_t)c1.w * 128 + lane * 2];
        ax += bf2f((ushortT)(u0 & 0xffff)) + bf2f((ushortT)(u1 & 0xffff))
            + bf2f((ushortT)(u2 & 0xffff)) + bf2f((ushortT)(u3 & 0xffff))
            + bf2f((ushortT)(u4 & 0xffff)) + bf2f((ushortT)(u5 & 0xffff))
            + bf2f((ushortT)(u6 & 0xffff)) + bf2f((ushortT)(u7 & 0xffff));
        ay += bf2f((ushortT)(u0 >> 16)) + bf2f((ushortT)(u1 >> 16))
            + bf2f((ushortT)(u2 >> 16)) + bf2f((ushortT)(u3 >> 16))
            + bf2f((ushortT)(u4 >> 16)) + bf2f((ushortT)(u5 >> 16))
            + bf2f((ushortT)(u6 >> 16)) + bf2f((ushortT)(u7 >> 16));
    }
    unsigned int o = ((unsigned int)f2bf(ay) << 16) | (unsigned int)f2bf(ax);
    *(unsigned int*)&T[(size_t)gid * 128 + lane * 2] = o;
}

// ---------------- GEMM: C = bf16(relu(A @ W + add)), 128 rows/block ----------------
__global__ __launch_bounds__(256) void k_gemm(const ushortT* __restrict__ A, const ushortT* __restrict__ Wt,
                                              const float* __restrict__ addv, ushortT* __restrict__ C) {
    __shared__ ushortT w[128 * 136];         // Wt staged, row stride 136 (2-way bank alias only)
    int tid = threadIdx.x;
#pragma unroll
    for (int it = 0; it < 8; ++it) {
        int idx = (it * 256 + tid) * 8;      // element index, 16B per thread
        int n = idx >> 7, k = idx & 127;
        *(uint4v*)&w[n * 136 + k] = *(const uint4v*)&Wt[idx];
    }
    __syncthreads();
    int wave = tid >> 6, lane = tid & 63;
    int quad = lane >> 4, l16 = lane & 15;
    int row0 = blockIdx.x * 128 + wave * 32;
    f32x4 acc[2][8];
#pragma unroll
    for (int t2 = 0; t2 < 2; ++t2)
#pragma unroll
        for (int c = 0; c < 8; ++c) acc[t2][c] = (f32x4){0.f, 0.f, 0.f, 0.f};
    const ushortT* ar0 = A + (size_t)(row0 + l16) * 128;
    const ushortT* ar1 = A + (size_t)(row0 + 16 + l16) * 128;
#pragma unroll
    for (int kc = 0; kc < 4; ++kc) {
        bf16x8 a0 = *(const bf16x8*)&ar0[kc * 32 + quad * 8];
        bf16x8 a1 = *(const bf16x8*)&ar1[kc * 32 + quad * 8];
#pragma unroll
        for (int c = 0; c < 8; ++c) {
            bf16x8 bf = *(const bf16x8*)&w[(c * 16 + l16) * 136 + kc * 32 + quad * 8];
            acc[0][c] = __builtin_amdgcn_mfma_f32_16x16x32_bf16(a0, bf, acc[0][c], 0, 0, 0);
            acc[1][c] = __builtin_amdgcn_mfma_f32_16x16x32_bf16(a1, bf, acc[1][c], 0, 0, 0);
        }
    }
#pragma unroll
    for (int t2 = 0; t2 < 2; ++t2) {
#pragma unroll
        for (int c = 0; c < 8; ++c) {
            int n = c * 16 + l16;
            float ad = addv[n];
#pragma unroll
            for (int r = 0; r < 4; ++r) {
                int row = row0 + t2 * 16 + quad * 4 + r;
                if (row < N_NODES) {
                    float y = acc[t2][c][r] + ad;
                    y = y > 0.f ? y : 0.f;
                    C[(size_t)row * 128 + n] = f2bf(y);
                }
            }
        }
    }
}

// ------- pooling: wave-per-row-slice run-length accumulation, unroll-4 -------
#define POOL_CHUNK 512
__global__ __launch_bounds__(256) void k_pool(const ushortT* __restrict__ H, const int* __restrict__ batch,
                                              float* __restrict__ P, int off) {
    int n0 = blockIdx.x * POOL_CHUNK;
    int lane = threadIdx.x & 63;
    int s = threadIdx.x >> 6;                // 4 interleaved node streams (one per wave)
    int d2 = lane * 2;                       // two dims per thread
    int end = n0 + POOL_CHUNK;
    if (end > N_NODES) end = N_NODES;
    float ax = 0.f, ay = 0.f;
    int cur = -1;
    int i = n0 + s;
    for (; i + 12 < end; i += 16) {
        int g0 = batch[i], g1 = batch[i + 4], g2 = batch[i + 8], g3 = batch[i + 12];
        unsigned int u0 = *(const unsigned int*)&H[(size_t)i * 128 + d2];
        unsigned int u1 = *(const unsigned int*)&H[(size_t)(i + 4) * 128 + d2];
        unsigned int u2 = *(const unsigned int*)&H[(size_t)(i + 8) * 128 + d2];
        unsigned int u3 = *(const unsigned int*)&H[(size_t)(i + 12) * 128 + d2];
        int gs[4] = {g0, g1, g2, g3};
        unsigned int us[4] = {u0, u1, u2, u3};
#pragma unroll
        for (int q = 0; q < 4; ++q) {
            if (gs[q] != cur) {
                if (cur >= 0) {
                    atomicAdd(&P[cur * 384 + off + d2], ax);
                    atomicAdd(&P[cur * 384 + off + d2 + 1], ay);
                }
                cur = gs[q];
                ax = 0.f; ay = 0.f;
            }
            ax += bf2f((ushortT)(us[q] & 0xffff));
            ay += bf2f((ushortT)(us[q] >> 16));
        }
    }
    for (; i < end; i += 4) {
        int gi = batch[i];
        unsigned int u = *(const unsigned int*)&H[(size_t)i * 128 + d2];
        if (gi != cur) {
            if (cur >= 0) {
                atomicAdd(&P[cur * 384 + off + d2], ax);
                atomicAdd(&P[cur * 384 + off + d2 + 1], ay);
            }
            cur = gi;
            ax = 0.f; ay = 0.f;
        }
        ax += bf2f((ushortT)(u & 0xffff));
        ay += bf2f((ushortT)(u >> 16));
    }
    if (cur >= 0) {
        atomicAdd(&P[cur * 384 + off + d2], ax);
        atomicAdd(&P[cur * 384 + off + d2 + 1], ay);
    }
}

// ---------------- head: out = relu(P @ W1 + b1) @ W2 + b2  (all fp32) ------------
__global__ __launch_bounds__(384) void k_head(const float* __restrict__ P, const float* __restrict__ W1,
                                              const float* __restrict__ B1, const float* __restrict__ W2,
                                              const float* __restrict__ B2, float* __restrict__ out) {
    __shared__ float pr[384];
    __shared__ float qr[384];
    int g = blockIdx.x, t = threadIdx.x;
    pr[t] = P[g * 384 + t];
    __syncthreads();
    float a = 0.f;
    for (int k = 0; k < 384; ++k) a += pr[k] * W1[k * 384 + t];
    a += B1[t];
    qr[t] = a > 0.f ? a : 0.f;
    __syncthreads();
    if (t < 10) {
        float o = 0.f;
        for (int k = 0; k < 384; ++k) o += qr[k] * W2[k * 10 + t];
        o += B2[t];
        out[g * 10 + t] = o;
    }
}

extern "C" void kernel_launch(void* const* d_in, const int* in_sizes, int n_in,
                              void* d_out, int out_size, void* d_ws, size_t ws_size,
                              hipStream_t stream) {
    const float* x     = (const float*)d_in[0];
    const int*   ei    = (const int*)d_in[1];
    const int*   srcA  = ei;
    const int*   dstA  = ei + N_EDGES;
    const int*   batch = (const int*)d_in[2];
    const float* c1_w1 = (const float*)d_in[3];
    const float* c1_b1 = (const float*)d_in[4];
    const float* c1_g  = (const float*)d_in[5];
    const float* c1_be = (const float*)d_in[6];
    const float* c1_w2 = (const float*)d_in[7];
    const float* c1_b2 = (const float*)d_in[8];
    const float* c2_w1 = (const float*)d_in[9];
    const float* c2_b1 = (const float*)d_in[10];
    const float* c2_g  = (const float*)d_in[11];
    const float* c2_be = (const float*)d_in[12];
    const float* c2_w2 = (const float*)d_in[13];
    const float* c2_b2 = (const float*)d_in[14];
    const float* c3_w1 = (const float*)d_in[15];
    const float* c3_b1 = (const float*)d_in[16];
    const float* c3_g  = (const float*)d_in[17];
    const float* c3_be = (const float*)d_in[18];
    const float* c3_w2 = (const float*)d_in[19];
    const float* c3_b2 = (const float*)d_in[20];
    const float* l1w   = (const float*)d_in[21];
    const float* l1b   = (const float*)d_in[22];
    const float* l2w   = (const float*)d_in[23];
    const float* l2b   = (const float*)d_in[24];
    float* out = (float*)d_out;

    size_t o = 0;
    char* base = (char*)d_ws;
    auto alloc = [&](size_t n) -> char* {
        char* p = base + o;
        o += (n + 255) & ~(size_t)255;
        return p;
    };
    ushortT* Wt    = (ushortT*)alloc(6 * 16384 * 2);
    float*   addv  = (float*)alloc(6 * 128 * 4);
    int*     deg   = (int*)alloc((size_t)N_NODES * 4);
    int*     cur   = (int*)alloc((size_t)N_NODES * 4);
    int*     tscan = (int*)alloc((size_t)100352 * 4);
    int*     bsum  = (int*)alloc(98 * 4);
    int*     boff  = (int*)alloc(98 * 4);
    int*     pst   = (int*)alloc((size_t)(N_NODES + 1) * 4);
    int*     colA  = (int*)alloc((size_t)COL_CAP * 4);
    ushortT* bufA  = (ushortT*)alloc((size_t)MPAD * 128 * 2);   // agg output
    ushortT* bufB  = (ushortT*)alloc((size_t)MPAD * 128 * 2);   // gemm1 output
    ushortT* bufC  = (ushortT*)alloc((size_t)MPAD * 128 * 2);   // x(bf16) / gemm2 output
    float*   pbuf  = (float*)alloc((size_t)N_GRAPHS * 384 * 4);

    hipMemsetAsync(deg, 0, (size_t)N_NODES * 4, stream);
    hipMemsetAsync(cur, 0, (size_t)N_NODES * 4, stream);
    hipMemsetAsync(pbuf, 0, (size_t)N_GRAPHS * 384 * 4, stream);

    k_prep<<<386, 256, 0, stream>>>(c1_w1, c1_w2, c2_w1, c2_w2, c3_w1, c3_w2,
                                    c1_b1, c1_g, c1_be, c1_b2,
                                    c2_b1, c2_g, c2_be, c2_b2,
                                    c3_b1, c3_g, c3_be, c3_b2,
                                    Wt, addv);
    k_cvt<<<(MPAD * 128 / 4 + 255) / 256, 256, 0, stream>>>(x, bufC);
    k_count<<<N_EDGES / 256, 256, 0, stream>>>(dstA, deg);
    k_scan1<<<98, 1024, 0, stream>>>(deg, tscan, bsum);
    k_scan2<<<1, 64, 0, stream>>>(bsum, boff);
    k_scan3<<<391, 256, 0, stream>>>(tscan, boff, pst);
    k_fill<<<N_EDGES / 256, 256, 0, stream>>>(srcA, dstA, pst, cur, colA);
    k_padfill<<<391, 256, 0, stream>>>(deg, pst, colA);

    for (int L = 0; L < 3; ++L) {
        k_agg<<<MPAD / 4, 256, 0, stream>>>(bufC, pst, colA, bufA);
        k_gemm<<<MPAD / 128, 256, 0, stream>>>(bufA, Wt + (2 * L) * 16384, addv + (2 * L) * 128, bufB);
        k_gemm<<<MPAD / 128, 256, 0, stream>>>(bufB, Wt + (2 * L + 1) * 16384, addv + (2 * L + 1) * 128, bufC);
        k_pool<<<(N_NODES + POOL_CHUNK - 1) / POOL_CHUNK, 256, 0, stream>>>(bufC, batch, pbuf, L * 128);
    }
    k_head<<<N_GRAPHS, 384, 0, stream>>>(pbuf, l1w, l1b, l2w, l2b, out);
}

// Round 5
// 596.663 us; speedup vs baseline: 1.8718x; 1.1333x over previous
//
#include <hip/hip_runtime.h>

#define N_NODES 100000
#define N_EDGES 1600000
#define N_GRAPHS 512
#define MPAD 100096      // 782 * 128
#define COL_CAP 2400000  // N_EDGES + 8*N_NODES worst case
#define NBUCK 782        // buckets of 128 nodes (dst >> 7)
#define BCAP 3072        // per-bucket capacity; mean 2046, sigma ~45 -> 22 sigma margin

typedef unsigned short ushortT;
typedef __attribute__((ext_vector_type(8))) short bf16x8;
typedef __attribute__((ext_vector_type(4))) float f32x4;
typedef __attribute__((ext_vector_type(4))) unsigned int uint4v;

__device__ inline float bf2f(ushortT u) {
    unsigned int x = ((unsigned int)u) << 16;
    return __builtin_bit_cast(float, x);
}
__device__ inline ushortT f2bf(float f) {
    unsigned int x = __builtin_bit_cast(unsigned int, f);
    unsigned int r = (x + 0x7fffu + ((x >> 16) & 1u)) >> 16;
    return (ushortT)r;
}

// ---------------- prep: transpose fp32 weights -> bf16 Wt (fold BN scale), build add vectors ----
__global__ __launch_bounds__(256) void k_prep(
    const float* __restrict__ w11, const float* __restrict__ w12,
    const float* __restrict__ w21, const float* __restrict__ w22,
    const float* __restrict__ w31, const float* __restrict__ w32,
    const float* __restrict__ b11, const float* __restrict__ g1, const float* __restrict__ be1, const float* __restrict__ b12,
    const float* __restrict__ b21, const float* __restrict__ g2, const float* __restrict__ be2, const float* __restrict__ b22,
    const float* __restrict__ b31, const float* __restrict__ g3, const float* __restrict__ be3, const float* __restrict__ b32,
    ushortT* __restrict__ Wt, float* __restrict__ addv)
{
    int bid = blockIdx.x, t = threadIdx.x;
    const float rs = rsqrtf(1.0f + 1e-5f);
    if (bid < 384) {
        int idx = bid * 256 + t;             // 0..98303
        int m = idx >> 14;                   // matrix 0..5
        int r = idx & 16383;
        int k = r & 127;
        int n = r >> 7;
        const float* W = (m == 0) ? w11 : (m == 1) ? w12 : (m == 2) ? w21
                       : (m == 3) ? w22 : (m == 4) ? w31 : w32;
        float v = W[k * 128 + n];
        if ((m & 1) == 0) {                  // a "w1": fold BN scale per out-col n
            const float* gm = (m == 0) ? g1 : (m == 2) ? g2 : g3;
            v *= gm[n] * rs;
        }
        Wt[m * 16384 + n * 128 + k] = f2bf(v);
    } else if (bid == 384) {                 // gemm1 adds: b1*s + beta
        if (t < 384) {
            int L = t >> 7, n = t & 127;
            const float* bb = (L == 0) ? b11 : (L == 1) ? b21 : b31;
            const float* gm = (L == 0) ? g1 : (L == 1) ? g2 : g3;
            const float* be = (L == 0) ? be1 : (L == 1) ? be2 : be3;
            float s = gm[n] * rs;
            addv[(2 * L) * 128 + n] = bb[n] * s + be[n];
        }
    } else {                                 // gemm2 adds: b2
        if (t < 384) {
            int L = t >> 7, n = t & 127;
            const float* bb = (L == 0) ? b12 : (L == 1) ? b22 : b32;
            addv[(2 * L + 1) * 128 + n] = bb[n];
        }
    }
}

// ---------------- x (fp32) -> bf16, plus zeroed padding rows ----------------
__global__ __launch_bounds__(256) void k_cvt(const float* __restrict__ X, ushortT* __restrict__ Y) {
    size_t i = ((size_t)blockIdx.x * 256 + threadIdx.x) * 4;
    if (i >= (size_t)MPAD * 128) return;
    unsigned long long o = 0ull;
    if (i < (size_t)N_NODES * 128) {
        float4 v = *(const float4*)&X[i];
        o = (unsigned long long)f2bf(v.x)
          | ((unsigned long long)f2bf(v.y) << 16)
          | ((unsigned long long)f2bf(v.z) << 32)
          | ((unsigned long long)f2bf(v.w) << 48);
    }
    *(unsigned long long*)&Y[i] = o;
}

// ------- bucket binning: scatter (src,dst) into dst-range buckets, L2-local writes -------
__global__ __launch_bounds__(256) void kb_scatter(const int* __restrict__ src, const int* __restrict__ dst,
                                                  int* __restrict__ gcur, int2* __restrict__ ebin) {
    __shared__ int lcnt[NBUCK];
    __shared__ int lbase[NBUCK];
    int t = threadIdx.x;
    int e0 = blockIdx.x * (N_EDGES / 256);
    int e1 = e0 + (N_EDGES / 256);
    for (int i = t; i < NBUCK; i += 256) lcnt[i] = 0;
    __syncthreads();
    for (int e = e0 + t; e < e1; e += 256) atomicAdd(&lcnt[dst[e] >> 7], 1);
    __syncthreads();
    for (int i = t; i < NBUCK; i += 256) {
        int c = lcnt[i];
        lbase[i] = c ? atomicAdd(&gcur[i], c) : 0;
    }
    __syncthreads();
    for (int i = t; i < NBUCK; i += 256) lcnt[i] = 0;
    __syncthreads();
    for (int e = e0 + t; e < e1; e += 256) {
        int d = dst[e];
        int b = d >> 7;
        int off = atomicAdd(&lcnt[b], 1);
        ebin[(size_t)b * BCAP + lbase[b] + off] = make_int2(src[e], d);
    }
}

// ------- per-bucket degree count: LDS histogram, no global atomics -------
__global__ __launch_bounds__(256) void kb_count(const int2* __restrict__ ebin, const int* __restrict__ gcur,
                                                int* __restrict__ deg) {
    __shared__ int cnt[128];
    int b = blockIdx.x, t = threadIdx.x;
    if (t < 128) cnt[t] = 0;
    __syncthreads();
    int m = gcur[b];
    const int2* eb = ebin + (size_t)b * BCAP;
    for (int e = t; e < m; e += 256) atomicAdd(&cnt[eb[e].y & 127], 1);
    __syncthreads();
    if (t < 128) {
        int node = b * 128 + t;
        if (node < N_NODES) deg[node] = cnt[t];
    }
}

__global__ __launch_bounds__(1024) void k_scan1(const int* __restrict__ deg, int* __restrict__ tscan,
                                                int* __restrict__ bsum) {
    __shared__ int s[1024];
    int t = threadIdx.x;
    int i = blockIdx.x * 1024 + t;
    int v = (i < N_NODES) ? ((deg[i] + 7) & ~7) : 0;   // padded degree
    s[t] = v;
    __syncthreads();
    for (int off = 1; off < 1024; off <<= 1) {
        int tmp = (t >= off) ? s[t - off] : 0;
        __syncthreads();
        s[t] += tmp;
        __syncthreads();
    }
    tscan[i] = s[t];
    if (t == 1023) bsum[blockIdx.x] = s[1023];
}

__global__ void k_scan2(const int* __restrict__ bsum, int* __restrict__ boff) {
    if (threadIdx.x == 0 && blockIdx.x == 0) {
        int run = 0;
        for (int b = 0; b < 98; ++b) { boff[b] = run; run += bsum[b]; }
    }
}

__global__ __launch_bounds__(256) void k_scan3(const int* __restrict__ tscan, const int* __restrict__ boff,
                                               int* __restrict__ pstart) {
    int i = blockIdx.x * 256 + threadIdx.x;
    if (i > N_NODES) return;
    pstart[i] = (i == 0) ? 0 : tscan[i - 1] + boff[(i - 1) >> 10];
}

// ------- per-bucket CSR fill: LDS cursors, writes confined to bucket's CSR window -------
__global__ __launch_bounds__(256) void kb_fill(const int2* __restrict__ ebin, const int* __restrict__ gcur,
                                               const int* __restrict__ pstart, int* __restrict__ col) {
    __shared__ int ps[128];
    __shared__ int cur[128];
    int b = blockIdx.x, t = threadIdx.x;
    if (t < 128) {
        int node = b * 128 + t;
        ps[t] = (node < N_NODES) ? pstart[node] : 0;
        cur[t] = 0;
    }
    __syncthreads();
    int m = gcur[b];
    const int2* eb = ebin + (size_t)b * BCAP;
    for (int e = t; e < m; e += 256) {
        int2 sd = eb[e];
        int idx = sd.y & 127;
        int pos = ps[idx] + atomicAdd(&cur[idx], 1);
        col[pos] = sd.x;
    }
}

// pad each node's list up to multiple of 8 with index N_NODES (a guaranteed-zero row)
__global__ __launch_bounds__(256) void k_padfill(const int* __restrict__ deg, const int* __restrict__ pstart,
                                                 int* __restrict__ col) {
    int i = blockIdx.x * 256 + threadIdx.x;
    if (i >= N_NODES) return;
    int s = pstart[i] + deg[i];
    int e = pstart[i + 1];
    for (int j = s; j < e; ++j) col[j] = N_NODES;
}

// ------- aggregation (bf16): T[i] = bf16(X[i] + sum_j X[col[j]]), unroll-8 branch-free -------
__global__ __launch_bounds__(256) void k_agg(const ushortT* __restrict__ X, const int* __restrict__ pstart,
                                             const int* __restrict__ col, ushortT* __restrict__ T) {
    int gid = blockIdx.x * 4 + (threadIdx.x >> 6);
    int lane = threadIdx.x & 63;
    if (gid >= MPAD) return;
    if (gid >= N_NODES) {                    // zero padding rows (MFMA A-operand hygiene)
        *(unsigned int*)&T[(size_t)gid * 128 + lane * 2] = 0u;
        return;
    }
    int lo = pstart[gid], hi = pstart[gid + 1];
    unsigned int v = *(const unsigned int*)&X[(size_t)gid * 128 + lane * 2];
    float ax = bf2f((ushortT)(v & 0xffff));
    float ay = bf2f((ushortT)(v >> 16));
    for (int j = lo; j < hi; j += 8) {       // (hi-lo) % 8 == 0 by construction
        int4 c0 = *(const int4*)&col[j];
        int4 c1 = *(const int4*)&col[j + 4];
        unsigned int u0 = *(const unsigned int*)&X[(size_t)c0.x * 128 + lane * 2];
        unsigned int u1 = *(const unsigned int*)&X[(size_t)c0.y * 128 + lane * 2];
        unsigned int u2 = *(const unsigned int*)&X[(size_t)c0.z * 128 + lane * 2];
        unsigned int u3 = *(const unsigned int*)&X[(size_t)c0.w * 128 + lane * 2];
        unsigned int u4 = *(const unsigned int*)&X[(size_t)c1.x * 128 + lane * 2];
        unsigned int u5 = *(const unsigned int*)&X[(size_t)c1.y * 128 + lane * 2];
        unsigned int u6 = *(const unsigned int*)&X[(size_t)c1.z * 128 + lane * 2];
        unsigned int u7 = *(const unsigned int*)&X[(size_t)c1.w * 128 + lane * 2];
        ax += bf2f((ushortT)(u0 & 0xffff)) + bf2f((ushortT)(u1 & 0xffff))
            + bf2f((ushortT)(u2 & 0xffff)) + bf2f((ushortT)(u3 & 0xffff))
            + bf2f((ushortT)(u4 & 0xffff)) + bf2f((ushortT)(u5 & 0xffff))
            + bf2f((ushortT)(u6 & 0xffff)) + bf2f((ushortT)(u7 & 0xffff));
        ay += bf2f((ushortT)(u0 >> 16)) + bf2f((ushortT)(u1 >> 16))
            + bf2f((ushortT)(u2 >> 16)) + bf2f((ushortT)(u3 >> 16))
            + bf2f((ushortT)(u4 >> 16)) + bf2f((ushortT)(u5 >> 16))
            + bf2f((ushortT)(u6 >> 16)) + bf2f((ushortT)(u7 >> 16));
    }
    unsigned int o = ((unsigned int)f2bf(ay) << 16) | (unsigned int)f2bf(ax);
    *(unsigned int*)&T[(size_t)gid * 128 + lane * 2] = o;
}

// ---------------- GEMM: C = bf16(relu(A @ W + add)), 128 rows/block ----------------
__global__ __launch_bounds__(256) void k_gemm(const ushortT* __restrict__ A, const ushortT* __restrict__ Wt,
                                              const float* __restrict__ addv, ushortT* __restrict__ C) {
    __shared__ ushortT w[128 * 136];         // Wt staged, row stride 136 (2-way bank alias only)
    int tid = threadIdx.x;
#pragma unroll
    for (int it = 0; it < 8; ++it) {
        int idx = (it * 256 + tid) * 8;      // element index, 16B per thread
        int n = idx >> 7, k = idx & 127;
        *(uint4v*)&w[n * 136 + k] = *(const uint4v*)&Wt[idx];
    }
    __syncthreads();
    int wave = tid >> 6, lane = tid & 63;
    int quad = lane >> 4, l16 = lane & 15;
    int row0 = blockIdx.x * 128 + wave * 32;
    f32x4 acc[2][8];
#pragma unroll
    for (int t2 = 0; t2 < 2; ++t2)
#pragma unroll
        for (int c = 0; c < 8; ++c) acc[t2][c] = (f32x4){0.f, 0.f, 0.f, 0.f};
    const ushortT* ar0 = A + (size_t)(row0 + l16) * 128;
    const ushortT* ar1 = A + (size_t)(row0 + 16 + l16) * 128;
#pragma unroll
    for (int kc = 0; kc < 4; ++kc) {
        bf16x8 a0 = *(const bf16x8*)&ar0[kc * 32 + quad * 8];
        bf16x8 a1 = *(const bf16x8*)&ar1[kc * 32 + quad * 8];
#pragma unroll
        for (int c = 0; c < 8; ++c) {
            bf16x8 bf = *(const bf16x8*)&w[(c * 16 + l16) * 136 + kc * 32 + quad * 8];
            acc[0][c] = __builtin_amdgcn_mfma_f32_16x16x32_bf16(a0, bf, acc[0][c], 0, 0, 0);
            acc[1][c] = __builtin_amdgcn_mfma_f32_16x16x32_bf16(a1, bf, acc[1][c], 0, 0, 0);
        }
    }
#pragma unroll
    for (int t2 = 0; t2 < 2; ++t2) {
#pragma unroll
        for (int c = 0; c < 8; ++c) {
            int n = c * 16 + l16;
            float ad = addv[n];
#pragma unroll
            for (int r = 0; r < 4; ++r) {
                int row = row0 + t2 * 16 + quad * 4 + r;
                if (row < N_NODES) {
                    float y = acc[t2][c][r] + ad;
                    y = y > 0.f ? y : 0.f;
                    C[(size_t)row * 128 + n] = f2bf(y);
                }
            }
        }
    }
}

// ------- pooling: wave-per-row-slice run-length accumulation, unroll-4 -------
#define POOL_CHUNK 512
__global__ __launch_bounds__(256) void k_pool(const ushortT* __restrict__ H, const int* __restrict__ batch,
                                              float* __restrict__ P, int off) {
    int n0 = blockIdx.x * POOL_CHUNK;
    int lane = threadIdx.x & 63;
    int s = threadIdx.x >> 6;                // 4 interleaved node streams (one per wave)
    int d2 = lane * 2;                       // two dims per thread
    int end = n0 + POOL_CHUNK;
    if (end > N_NODES) end = N_NODES;
    float ax = 0.f, ay = 0.f;
    int cur = -1;
    int i = n0 + s;
    for (; i + 12 < end; i += 16) {
        int g0 = batch[i], g1 = batch[i + 4], g2 = batch[i + 8], g3 = batch[i + 12];
        unsigned int u0 = *(const unsigned int*)&H[(size_t)i * 128 + d2];
        unsigned int u1 = *(const unsigned int*)&H[(size_t)(i + 4) * 128 + d2];
        unsigned int u2 = *(const unsigned int*)&H[(size_t)(i + 8) * 128 + d2];
        unsigned int u3 = *(const unsigned int*)&H[(size_t)(i + 12) * 128 + d2];
        int gs[4] = {g0, g1, g2, g3};
        unsigned int us[4] = {u0, u1, u2, u3};
#pragma unroll
        for (int q = 0; q < 4; ++q) {
            if (gs[q] != cur) {
                if (cur >= 0) {
                    atomicAdd(&P[cur * 384 + off + d2], ax);
                    atomicAdd(&P[cur * 384 + off + d2 + 1], ay);
                }
                cur = gs[q];
                ax = 0.f; ay = 0.f;
            }
            ax += bf2f((ushortT)(us[q] & 0xffff));
            ay += bf2f((ushortT)(us[q] >> 16));
        }
    }
    for (; i < end; i += 4) {
        int gi = batch[i];
        unsigned int u = *(const unsigned int*)&H[(size_t)i * 128 + d2];
        if (gi != cur) {
            if (cur >= 0) {
                atomicAdd(&P[cur * 384 + off + d2], ax);
                atomicAdd(&P[cur * 384 + off + d2 + 1], ay);
            }
            cur = gi;
            ax = 0.f; ay = 0.f;
        }
        ax += bf2f((ushortT)(u & 0xffff));
        ay += bf2f((ushortT)(u >> 16));
    }
    if (cur >= 0) {
        atomicAdd(&P[cur * 384 + off + d2], ax);
        atomicAdd(&P[cur * 384 + off + d2 + 1], ay);
    }
}

// ---------------- head: out = relu(P @ W1 + b1) @ W2 + b2  (all fp32) ------------
__global__ __launch_bounds__(384) void k_head(const float* __restrict__ P, const float* __restrict__ W1,
                                              const float* __restrict__ B1, const float* __restrict__ W2,
                                              const float* __restrict__ B2, float* __restrict__ out) {
    __shared__ float pr[384];
    __shared__ float qr[384];
    int g = blockIdx.x, t = threadIdx.x;
    pr[t] = P[g * 384 + t];
    __syncthreads();
    float a = 0.f;
    for (int k = 0; k < 384; ++k) a += pr[k] * W1[k * 384 + t];
    a += B1[t];
    qr[t] = a > 0.f ? a : 0.f;
    __syncthreads();
    if (t < 10) {
        float o = 0.f;
        for (int k = 0; k < 384; ++k) o += qr[k] * W2[k * 10 + t];
        o += B2[t];
        out[g * 10 + t] = o;
    }
}

extern "C" void kernel_launch(void* const* d_in, const int* in_sizes, int n_in,
                              void* d_out, int out_size, void* d_ws, size_t ws_size,
                              hipStream_t stream) {
    const float* x     = (const float*)d_in[0];
    const int*   ei    = (const int*)d_in[1];
    const int*   srcA  = ei;
    const int*   dstA  = ei + N_EDGES;
    const int*   batch = (const int*)d_in[2];
    const float* c1_w1 = (const float*)d_in[3];
    const float* c1_b1 = (const float*)d_in[4];
    const float* c1_g  = (const float*)d_in[5];
    const float* c1_be = (const float*)d_in[6];
    const float* c1_w2 = (const float*)d_in[7];
    const float* c1_b2 = (const float*)d_in[8];
    const float* c2_w1 = (const float*)d_in[9];
    const float* c2_b1 = (const float*)d_in[10];
    const float* c2_g  = (const float*)d_in[11];
    const float* c2_be = (const float*)d_in[12];
    const float* c2_w2 = (const float*)d_in[13];
    const float* c2_b2 = (const float*)d_in[14];
    const float* c3_w1 = (const float*)d_in[15];
    const float* c3_b1 = (const float*)d_in[16];
    const float* c3_g  = (const float*)d_in[17];
    const float* c3_be = (const float*)d_in[18];
    const float* c3_w2 = (const float*)d_in[19];
    const float* c3_b2 = (const float*)d_in[20];
    const float* l1w   = (const float*)d_in[21];
    const float* l1b   = (const float*)d_in[22];
    const float* l2w   = (const float*)d_in[23];
    const float* l2b   = (const float*)d_in[24];
    float* out = (float*)d_out;

    size_t o = 0;
    char* base = (char*)d_ws;
    auto alloc = [&](size_t n) -> char* {
        char* p = base + o;
        o += (n + 255) & ~(size_t)255;
        return p;
    };
    ushortT* Wt    = (ushortT*)alloc(6 * 16384 * 2);
    float*   addv  = (float*)alloc(6 * 128 * 4);
    int*     deg   = (int*)alloc((size_t)N_NODES * 4);
    int*     gcur  = (int*)alloc((size_t)NBUCK * 4);
    int*     tscan = (int*)alloc((size_t)100352 * 4);
    int*     bsum  = (int*)alloc(98 * 4);
    int*     boff  = (int*)alloc(98 * 4);
    int*     pst   = (int*)alloc((size_t)(N_NODES + 1) * 4);
    int*     colA  = (int*)alloc((size_t)COL_CAP * 4);
    ushortT* bufA  = (ushortT*)alloc((size_t)MPAD * 128 * 2);   // agg output; ebin aliases this
    ushortT* bufB  = (ushortT*)alloc((size_t)MPAD * 128 * 2);   // gemm1 output
    ushortT* bufC  = (ushortT*)alloc((size_t)MPAD * 128 * 2);   // x(bf16) / gemm2 output
    float*   pbuf  = (float*)alloc((size_t)N_GRAPHS * 384 * 4);
    int2*    ebin  = (int2*)bufA;   // 782*3072*8 = 19.2 MB <= 25.6 MB; dead before first k_agg

    hipMemsetAsync(gcur, 0, (size_t)NBUCK * 4, stream);
    hipMemsetAsync(pbuf, 0, (size_t)N_GRAPHS * 384 * 4, stream);

    k_prep<<<386, 256, 0, stream>>>(c1_w1, c1_w2, c2_w1, c2_w2, c3_w1, c3_w2,
                                    c1_b1, c1_g, c1_be, c1_b2,
                                    c2_b1, c2_g, c2_be, c2_b2,
                                    c3_b1, c3_g, c3_be, c3_b2,
                                    Wt, addv);
    k_cvt<<<(MPAD * 128 / 4 + 255) / 256, 256, 0, stream>>>(x, bufC);
    kb_scatter<<<256, 256, 0, stream>>>(srcA, dstA, gcur, ebin);
    kb_count<<<NBUCK, 256, 0, stream>>>(ebin, gcur, deg);
    k_scan1<<<98, 1024, 0, stream>>>(deg, tscan, bsum);
    k_scan2<<<1, 64, 0, stream>>>(bsum, boff);
    k_scan3<<<391, 256, 0, stream>>>(tscan, boff, pst);
    kb_fill<<<NBUCK, 256, 0, stream>>>(ebin, gcur, pst, colA);
    k_padfill<<<391, 256, 0, stream>>>(deg, pst, colA);

    for (int L = 0; L < 3; ++L) {
        k_agg<<<MPAD / 4, 256, 0, stream>>>(bufC, pst, colA, bufA);
        k_gemm<<<MPAD / 128, 256, 0, stream>>>(bufA, Wt + (2 * L) * 16384, addv + (2 * L) * 128, bufB);
        k_gemm<<<MPAD / 128, 256, 0, stream>>>(bufB, Wt + (2 * L + 1) * 16384, addv + (2 * L + 1) * 128, bufC);
        k_pool<<<(N_NODES + POOL_CHUNK - 1) / POOL_CHUNK, 256, 0, stream>>>(bufC, batch, pbuf, L * 128);
    }
    k_head<<<N_GRAPHS, 384, 0, stream>>>(pbuf, l1w, l1b, l2w, l2b, out);
}